// Round 3
// baseline (11592.618 us; speedup 1.0000x reference)
//
#include <hip/hip_runtime.h>

typedef __attribute__((ext_vector_type(8))) short bf16x8;
typedef __attribute__((ext_vector_type(4))) float f32x4;
typedef __attribute__((ext_vector_type(4))) unsigned short u16x4;

#define Bdim 256
#define Sdim 141
#define Vdim 1000
#define Edim 256
#define Hdim 512
#define G4H  2048

__device__ __forceinline__ float bf2f(unsigned short u) {
    union { unsigned int i; float f; } x; x.i = ((unsigned int)u) << 16; return x.f;
}
__device__ __forceinline__ unsigned short f2bf(float f) {
    union { float f; unsigned int i; } x; x.f = f;
    unsigned int i = x.i;
    return (unsigned short)((i + 0x7FFFu + ((i >> 16) & 1u)) >> 16);  // RNE
}
__device__ __forceinline__ float sigmoid_f(float x) { return 1.f / (1.f + __expf(-x)); }
__device__ __forceinline__ float tanh_f(float x)    { return 1.f - 2.f / (__expf(2.f * x) + 1.f); }

// load 8 consecutive fp32 (16B-aligned) -> bf16x8 MFMA fragment
__device__ __forceinline__ bf16x8 cvt8(const float* p) {
    const float4 v0 = ((const float4*)p)[0];
    const float4 v1 = ((const float4*)p)[1];
    bf16x8 r;
    r[0] = (short)f2bf(v0.x); r[1] = (short)f2bf(v0.y);
    r[2] = (short)f2bf(v0.z); r[3] = (short)f2bf(v0.w);
    r[4] = (short)f2bf(v1.x); r[5] = (short)f2bf(v1.y);
    r[6] = (short)f2bf(v1.z); r[7] = (short)f2bf(v1.w);
    return r;
}

// ---------------------------------------------------------------------------
// Bulk fp32 -> bf16 (RNE), vectorized x4. n4 = element_count/4.
// ---------------------------------------------------------------------------
__global__ __launch_bounds__(256) void f32_to_bf16_4(
    const float4* __restrict__ src, u16x4* __restrict__ dst, int n4)
{
    const int i = blockIdx.x * 256 + threadIdx.x;
    if (i < n4) {
        const float4 v = src[i];
        u16x4 r;
        r[0] = f2bf(v.x); r[1] = f2bf(v.y); r[2] = f2bf(v.z); r[3] = f2bf(v.w);
        dst[i] = r;
    }
}

// ---------------------------------------------------------------------------
// C = A * B^T (+bias), fp32 inputs converted inline to bf16 for MFMA.
// A:[M,lda] fp32, Bw row n = B^T col n. Block 256 = 4 waves; tile 128x64;
// wave = 32x64 via 2x4 16x16x32 MFMA frags.
// A-frag: A[m=lane&15][k=quad*8+j]; B-frag: B[k=quad*8+j][n=lane&15];
// C/D: col=lane&15, row=quad*4+reg  (verified, m89/m92).
// ---------------------------------------------------------------------------
template <bool BF16OUT>
__global__ __launch_bounds__(256) void gemm_bt_f32in(
    const float* __restrict__ A, int lda, int M,
    const float* __restrict__ Bw, int ldb,
    void* __restrict__ Cv, int ldc,
    const float* __restrict__ bias0,
    const float* __restrict__ bias1,
    int K)
{
    const int m0 = blockIdx.x * 128;
    const int n0 = blockIdx.y * 64;
    const int w    = threadIdx.x >> 6;
    const int l    = threadIdx.x & 63;
    const int lr   = l & 15;
    const int quad = l >> 4;

    int ra0 = m0 + w * 32 + lr;
    int ra1 = ra0 + 16;
    ra0 = ra0 < M ? ra0 : M - 1;   // clamp loads for ragged M (stores guarded)
    ra1 = ra1 < M ? ra1 : M - 1;
    const float* pa0 = A + (size_t)ra0 * lda + quad * 8;
    const float* pa1 = A + (size_t)ra1 * lda + quad * 8;
    const float* pb[4];
#pragma unroll
    for (int nj = 0; nj < 4; ++nj)
        pb[nj] = Bw + (size_t)(n0 + nj * 16 + lr) * ldb + quad * 8;

    f32x4 acc[2][4];
#pragma unroll
    for (int mi = 0; mi < 2; ++mi)
#pragma unroll
        for (int nj = 0; nj < 4; ++nj)
            acc[mi][nj] = (f32x4){0.f, 0.f, 0.f, 0.f};

    for (int k = 0; k < K; k += 32) {
        bf16x8 a0 = cvt8(pa0 + k);
        bf16x8 a1 = cvt8(pa1 + k);
#pragma unroll
        for (int nj = 0; nj < 4; ++nj) {
            bf16x8 bb = cvt8(pb[nj] + k);
            acc[0][nj] = __builtin_amdgcn_mfma_f32_16x16x32_bf16(a0, bb, acc[0][nj], 0, 0, 0);
            acc[1][nj] = __builtin_amdgcn_mfma_f32_16x16x32_bf16(a1, bb, acc[1][nj], 0, 0, 0);
        }
    }

#pragma unroll
    for (int nj = 0; nj < 4; ++nj) {
        const int col = n0 + nj * 16 + lr;
        float bv = 0.f;
        if (bias0) bv += bias0[col];
        if (bias1) bv += bias1[col];
#pragma unroll
        for (int mi = 0; mi < 2; ++mi) {
            const int row = m0 + w * 32 + mi * 16 + quad * 4;
#pragma unroll
            for (int r = 0; r < 4; ++r) {
                if (row + r < M) {
                    const float v = acc[mi][nj][r] + bv;
                    if (BF16OUT)
                        ((unsigned short*)Cv)[(size_t)(row + r) * ldc + col] = f2bf(v);
                    else
                        ((float*)Cv)[(size_t)(row + r) * ldc + col] = v;
                }
            }
        }
    }
}

// ---------------------------------------------------------------------------
// Sync-free LSTM scan. 16 blocks; block owns batch rows r0..r0+15 for ALL 141
// steps — recurrence is row-local => NO inter-block communication, no grid
// barrier, no cross-XCD coherence reliance. h in LDS (bf16); c in registers.
// Per step: wave w computes gate w (16 rows x 512 cols) in 4 col-chunks of
// 128 via MFMA vs pre-converted bf16 W_hh; pointwise fuses emb/enc adds +
// cell update; h_t also streamed to hs for the later logits GEMM.
// ---------------------------------------------------------------------------
__global__ __launch_bounds__(256) void lstm_scan(
    const unsigned short* __restrict__ Whh,      // [2048,512] bf16 (pre-converted)
    const unsigned short* __restrict__ emb_proj, // [1000,2048] bf16
    const float* __restrict__ enc_proj,          // [256,2048] fp32 (biases folded)
    const int* __restrict__ tgt,                 // [256,141]
    unsigned short* __restrict__ hs)             // [141,256,512] bf16 (h_1..h_141)
{
    const int r0   = blockIdx.x * 16;
    const int w    = threadIdx.x >> 6;   // gate 0..3 (i,f,g,o)
    const int l    = threadIdx.x & 63;
    const int lr   = l & 15;
    const int quad = l >> 4;

    __shared__ unsigned short h_lds[16][520];    // stride 520: 2-way (free) banks
    __shared__ float g_lds[4][16][132];          // +4 pad: conflict-free C-store

    const int prow = threadIdx.x & 15;           // pointwise: batch row
    const int pc0  = (threadIdx.x >> 4) * 8;     // pointwise: col group in chunk

    for (int i = threadIdx.x; i < 16 * 520; i += 256)
        ((unsigned short*)h_lds)[i] = 0;         // h_0 = 0
    __syncthreads();

    float c_reg[32];                             // c_0 = 0 (32 cols/thread)
#pragma unroll
    for (int j = 0; j < 32; ++j) c_reg[j] = 0.f;

    const unsigned short* wbase = Whh + (size_t)(w * Hdim + lr) * Hdim + quad * 8;

    const int brow = r0 + prow;
    const float* encp = enc_proj + (size_t)brow * G4H;
    const int* tokp = tgt + (size_t)brow * Sdim;

    for (int t = 0; t < Sdim; ++t) {
        bf16x8 a[16];
#pragma unroll
        for (int k16 = 0; k16 < 16; ++k16)
            a[k16] = *(const bf16x8*)&h_lds[lr][k16 * 32 + quad * 8];
        __syncthreads();   // a[] reads complete before pointwise overwrites h_lds

        const int tok = tokp[t];
        const unsigned short* embp = emb_proj + (size_t)tok * G4H;

#pragma unroll 1
        for (int ch = 0; ch < 4; ++ch) {
#pragma unroll
            for (int nf = 0; nf < 8; ++nf) {
                f32x4 acc = (f32x4){0.f, 0.f, 0.f, 0.f};
                const unsigned short* bp = wbase + (size_t)(ch * 128 + nf * 16) * Hdim;
#pragma unroll
                for (int k16 = 0; k16 < 16; ++k16) {
                    bf16x8 bb = *(const bf16x8*)(bp + k16 * 32);
                    acc = __builtin_amdgcn_mfma_f32_16x16x32_bf16(a[k16], bb, acc, 0, 0, 0);
                }
#pragma unroll
                for (int r = 0; r < 4; ++r)
                    g_lds[w][quad * 4 + r][nf * 16 + lr] = acc[r];
            }
            __syncthreads();

            const int colg = ch * 128 + pc0;
            bf16x8 hv;
#pragma unroll
            for (int j = 0; j < 8; ++j) {
                const int col  = colg + j;
                const int lcol = pc0 + j;
                const float iv = g_lds[0][prow][lcol] + bf2f(embp[col])            + encp[col];
                const float fv = g_lds[1][prow][lcol] + bf2f(embp[Hdim + col])     + encp[Hdim + col];
                const float gv = g_lds[2][prow][lcol] + bf2f(embp[2 * Hdim + col]) + encp[2 * Hdim + col];
                const float ov = g_lds[3][prow][lcol] + bf2f(embp[3 * Hdim + col]) + encp[3 * Hdim + col];
                const float cn = sigmoid_f(fv) * c_reg[ch * 8 + j] + sigmoid_f(iv) * tanh_f(gv);
                c_reg[ch * 8 + j] = cn;
                hv[j] = (short)f2bf(sigmoid_f(ov) * tanh_f(cn));
            }
            *(bf16x8*)&h_lds[prow][colg] = hv;
            *(bf16x8*)(hs + (size_t)t * (Bdim * Hdim) + (size_t)brow * Hdim + colg) = hv;
            __syncthreads();   // g_lds reuse next chunk; h_lds complete before next a[]
        }
    }
}

// ---------------------------------------------------------------------------
// logits = hs[36096,512](bf16) * out_W^T(bf16) + out_b(fp32) -> fp32
// out[b][s][v], row m = s*256 + b.
// ---------------------------------------------------------------------------
__global__ __launch_bounds__(256) void gemm_logits(
    const unsigned short* __restrict__ A,    // hs [141*256, 512] bf16
    const unsigned short* __restrict__ W,    // out_W [1000,512] bf16 (pre-conv)
    const float* __restrict__ bias,          // out_b [1000] fp32
    float* __restrict__ out)                 // [256,141,1000] fp32
{
    const int m0 = blockIdx.x * 128;
    const int n0 = blockIdx.y * 64;
    const int w    = threadIdx.x >> 6;
    const int l    = threadIdx.x & 63;
    const int lr   = l & 15;
    const int quad = l >> 4;

    const unsigned short* pa0 = A + (size_t)(m0 + w * 32 + lr) * Hdim + quad * 8;
    const unsigned short* pa1 = pa0 + (size_t)16 * Hdim;
    const unsigned short* pb[4];
#pragma unroll
    for (int nj = 0; nj < 4; ++nj) {
        int rb = n0 + nj * 16 + lr;
        rb = rb < Vdim ? rb : Vdim - 1;   // clamp ragged N
        pb[nj] = W + (size_t)rb * Hdim + quad * 8;
    }

    f32x4 acc[2][4];
#pragma unroll
    for (int mi = 0; mi < 2; ++mi)
#pragma unroll
        for (int nj = 0; nj < 4; ++nj)
            acc[mi][nj] = (f32x4){0.f, 0.f, 0.f, 0.f};

    for (int k = 0; k < Hdim; k += 32) {
        bf16x8 a0 = *(const bf16x8*)(pa0 + k);
        bf16x8 a1 = *(const bf16x8*)(pa1 + k);
#pragma unroll
        for (int nj = 0; nj < 4; ++nj) {
            bf16x8 bb = *(const bf16x8*)(pb[nj] + k);
            acc[0][nj] = __builtin_amdgcn_mfma_f32_16x16x32_bf16(a0, bb, acc[0][nj], 0, 0, 0);
            acc[1][nj] = __builtin_amdgcn_mfma_f32_16x16x32_bf16(a1, bb, acc[1][nj], 0, 0, 0);
        }
    }

#pragma unroll
    for (int nj = 0; nj < 4; ++nj) {
        const int col = n0 + nj * 16 + lr;
        if (col >= Vdim) continue;
        const float bv = bias[col];
#pragma unroll
        for (int mi = 0; mi < 2; ++mi) {
            const int rowb = m0 + w * 32 + mi * 16 + quad * 4;
#pragma unroll
            for (int r = 0; r < 4; ++r) {
                const int row = rowb + r;            // row = s*256 + b
                const int s = row >> 8;
                const int b = row & 255;
                out[((size_t)b * Sdim + s) * Vdim + col] = acc[mi][nj][r] + bv;
            }
        }
    }
}

extern "C" void kernel_launch(void* const* d_in, const int* in_sizes, int n_in,
                              void* d_out, int out_size, void* d_ws, size_t ws_size,
                              hipStream_t stream) {
    // Reference dtypes: all float tensors are FP32; target_sequence is int32.
    const float* enc   = (const float*)d_in[0];
    const int*   tgt   = (const int*)d_in[1];
    const float* emb   = (const float*)d_in[2];
    const float* W_ih  = (const float*)d_in[3];
    const float* W_hh  = (const float*)d_in[4];
    const float* b_ih  = (const float*)d_in[5];
    const float* b_hh  = (const float*)d_in[6];
    // d_in[7..9]: attn_W / attn_b / v_w — dead code (softmax over 1 source pos)
    const float* out_W = (const float*)d_in[10];
    const float* out_b = (const float*)d_in[11];
    float* out = (float*)d_out;

    char* ws = (char*)d_ws;
    unsigned short* whh_bf  = (unsigned short*)ws;                      // 2,097,152 B
    unsigned short* outw_bf = (unsigned short*)(ws + 2097152);          // 1,024,000 B
    unsigned short* emb_proj = (unsigned short*)(ws + 3121152);         // 4,096,000 B
    float*          enc_proj = (float*)(ws + 7217152);                  // 2,097,152 B
    unsigned short* hs       = (unsigned short*)(ws + 9314304);         // 36,962,304 B
    // total ws use = 46,276,608 B

    // pre-convert the two repeatedly-read weights to bf16
    f32_to_bf16_4<<<dim3((262144 + 255) / 256), 256, 0, stream>>>(
        (const float4*)W_hh, (u16x4*)whh_bf, 262144);    // 2048*512/4
    f32_to_bf16_4<<<dim3((128000 + 255) / 256), 256, 0, stream>>>(
        (const float4*)out_W, (u16x4*)outw_bf, 128000);  // 1000*512/4

    // emb_proj = embedding @ W_ih[:, :E].T               (bf16, [1000,2048])
    gemm_bt_f32in<true><<<dim3(8, 32), 256, 0, stream>>>(
        emb, Edim, Vdim, W_ih, 2 * Edim, emb_proj, G4H, nullptr, nullptr, Edim);
    // enc_proj = encoder_output @ W_ih[:, E:].T + b_ih + b_hh   (fp32, [256,2048])
    gemm_bt_f32in<false><<<dim3(2, 32), 256, 0, stream>>>(
        enc, Edim, Bdim, W_ih + Edim, 2 * Edim, enc_proj, G4H, b_ih, b_hh, Edim);
    // sequential scan — sync-free across blocks (batch-parallel, 16 blocks)
    lstm_scan<<<dim3(16), 256, 0, stream>>>(whh_bf, emb_proj, enc_proj, tgt, hs);
    // logits = hs @ out_W.T + out_b   (fp32 out)
    gemm_logits<<<dim3(282, 16), 256, 0, stream>>>(hs, outw_bf, out_b, out);
}

// Round 4
// 6397.986 us; speedup vs baseline: 1.8119x; 1.8119x over previous
//
#include <hip/hip_runtime.h>

typedef __attribute__((ext_vector_type(8))) short bf16x8;
typedef __attribute__((ext_vector_type(4))) float f32x4;
typedef __attribute__((ext_vector_type(4))) unsigned short u16x4;

#define Bdim 256
#define Sdim 141
#define Vdim 1000
#define Edim 256
#define Hdim 512
#define G4H  2048

__device__ __forceinline__ float bf2f(unsigned short u) {
    union { unsigned int i; float f; } x; x.i = ((unsigned int)u) << 16; return x.f;
}
__device__ __forceinline__ unsigned short f2bf(float f) {
    union { float f; unsigned int i; } x; x.f = f;
    unsigned int i = x.i;
    return (unsigned short)((i + 0x7FFFu + ((i >> 16) & 1u)) >> 16);  // RNE
}
__device__ __forceinline__ float sigmoid_f(float x) { return 1.f / (1.f + __expf(-x)); }
__device__ __forceinline__ float tanh_f(float x)    { return 1.f - 2.f / (__expf(2.f * x) + 1.f); }

__device__ __forceinline__ bf16x8 cvt8(const float* p) {
    const float4 v0 = ((const float4*)p)[0];
    const float4 v1 = ((const float4*)p)[1];
    bf16x8 r;
    r[0] = (short)f2bf(v0.x); r[1] = (short)f2bf(v0.y);
    r[2] = (short)f2bf(v0.z); r[3] = (short)f2bf(v0.w);
    r[4] = (short)f2bf(v1.x); r[5] = (short)f2bf(v1.y);
    r[6] = (short)f2bf(v1.z); r[7] = (short)f2bf(v1.w);
    return r;
}

// ---------------------------------------------------------------------------
// Bulk fp32 -> bf16 (RNE), vectorized x4.
// ---------------------------------------------------------------------------
__global__ __launch_bounds__(256) void f32_to_bf16_4(
    const float4* __restrict__ src, u16x4* __restrict__ dst, int n4)
{
    const int i = blockIdx.x * 256 + threadIdx.x;
    if (i < n4) {
        const float4 v = src[i];
        u16x4 r;
        r[0] = f2bf(v.x); r[1] = f2bf(v.y); r[2] = f2bf(v.z); r[3] = f2bf(v.w);
        dst[i] = r;
    }
}

// ---------------------------------------------------------------------------
// C = A * B^T (+bias), fp32 inputs converted inline to bf16 for MFMA.
// Tile 128x64, 4 waves. Layouts verified (m89/m92).
// ---------------------------------------------------------------------------
template <bool BF16OUT>
__global__ __launch_bounds__(256) void gemm_bt_f32in(
    const float* __restrict__ A, int lda, int M,
    const float* __restrict__ Bw, int ldb,
    void* __restrict__ Cv, int ldc,
    const float* __restrict__ bias0,
    const float* __restrict__ bias1,
    int K)
{
    const int m0 = blockIdx.x * 128;
    const int n0 = blockIdx.y * 64;
    const int w    = threadIdx.x >> 6;
    const int l    = threadIdx.x & 63;
    const int lr   = l & 15;
    const int quad = l >> 4;

    int ra0 = m0 + w * 32 + lr;
    int ra1 = ra0 + 16;
    ra0 = ra0 < M ? ra0 : M - 1;
    ra1 = ra1 < M ? ra1 : M - 1;
    const float* pa0 = A + (size_t)ra0 * lda + quad * 8;
    const float* pa1 = A + (size_t)ra1 * lda + quad * 8;
    const float* pb[4];
#pragma unroll
    for (int nj = 0; nj < 4; ++nj)
        pb[nj] = Bw + (size_t)(n0 + nj * 16 + lr) * ldb + quad * 8;

    f32x4 acc[2][4];
#pragma unroll
    for (int mi = 0; mi < 2; ++mi)
#pragma unroll
        for (int nj = 0; nj < 4; ++nj)
            acc[mi][nj] = (f32x4){0.f, 0.f, 0.f, 0.f};

    for (int k = 0; k < K; k += 32) {
        bf16x8 a0 = cvt8(pa0 + k);
        bf16x8 a1 = cvt8(pa1 + k);
#pragma unroll
        for (int nj = 0; nj < 4; ++nj) {
            bf16x8 bb = cvt8(pb[nj] + k);
            acc[0][nj] = __builtin_amdgcn_mfma_f32_16x16x32_bf16(a0, bb, acc[0][nj], 0, 0, 0);
            acc[1][nj] = __builtin_amdgcn_mfma_f32_16x16x32_bf16(a1, bb, acc[1][nj], 0, 0, 0);
        }
    }

#pragma unroll
    for (int nj = 0; nj < 4; ++nj) {
        const int col = n0 + nj * 16 + lr;
        float bv = 0.f;
        if (bias0) bv += bias0[col];
        if (bias1) bv += bias1[col];
#pragma unroll
        for (int mi = 0; mi < 2; ++mi) {
            const int row = m0 + w * 32 + mi * 16 + quad * 4;
#pragma unroll
            for (int r = 0; r < 4; ++r) {
                if (row + r < M) {
                    const float v = acc[mi][nj][r] + bv;
                    if (BF16OUT)
                        ((unsigned short*)Cv)[(size_t)(row + r) * ldc + col] = f2bf(v);
                    else
                        ((float*)Cv)[(size_t)(row + r) * ldc + col] = v;
                }
            }
        }
    }
}

// ---------------------------------------------------------------------------
// Per-batch-tile grid barrier: 64 blocks (same bi) rendezvous. Monotonic
// counters (NO resets -> no reset race): group g done in epoch `target` when
// its counter reaches target*16; tile root done when it reaches target*4;
// then epoch[bi] = target. Agent-scope fences for cross-XCD h visibility.
// Bounded spin: a logic bug gives a finite wrong answer, not a hang.
// ---------------------------------------------------------------------------
__device__ __forceinline__ void tile_sync(unsigned* bar, int bi, int blk, unsigned target) {
    __syncthreads();
    if (threadIdx.x == 0) {
        __builtin_amdgcn_fence(__ATOMIC_RELEASE, "agent");   // flush h stores device-wide
        unsigned* ep   = bar + bi * 32;                      // epoch line per tile
        unsigned* root = bar + 128 + bi * 32;                // root ctr per tile
        unsigned* gc   = bar + 256 + (blk >> 4) * 32;        // 16 groups of 16 blocks
        unsigned prev = __hip_atomic_fetch_add(gc, 1u, __ATOMIC_ACQ_REL, __HIP_MEMORY_SCOPE_AGENT);
        if (prev == target * 16u - 1u) {                     // last of my 16-group
            unsigned rprev = __hip_atomic_fetch_add(root, 1u, __ATOMIC_ACQ_REL, __HIP_MEMORY_SCOPE_AGENT);
            if (rprev == target * 4u - 1u)                   // last of the 4 groups
                __hip_atomic_store(ep, target, __ATOMIC_RELEASE, __HIP_MEMORY_SCOPE_AGENT);
        }
        int guard = 0;
        while (__hip_atomic_load(ep, __ATOMIC_ACQUIRE, __HIP_MEMORY_SCOPE_AGENT) < target
               && ++guard < (1 << 22))
            __builtin_amdgcn_s_sleep(2);
        __builtin_amdgcn_fence(__ATOMIC_ACQUIRE, "agent");   // invalidate stale caches
    }
    __syncthreads();
}

// ---------------------------------------------------------------------------
// Weights-stationary LSTM scan. 256 blocks = 4 batch-tiles(64 rows) x 64
// h-tiles(8 h-cols). Block's W_hh slice (4 gates x 8 cols x 512 k = 32 KB)
// lives in LDS in fragment-major order (conflict-free ds_read_b128). Per
// step: MFMA gates[64 x 32] from h_t (global) x W(LDS); pointwise cell
// update (c in regs); write h slice; per-batch-tile barrier (h-exchange is
// only within a batch tile). t=0 skips MFMA (h_0 = 0).
// ---------------------------------------------------------------------------
__global__ __launch_bounds__(256) void lstm_scan(
    const unsigned short* __restrict__ Whh,      // [2048,512] bf16
    const unsigned short* __restrict__ emb_proj, // [1000,2048] bf16
    const float* __restrict__ enc_proj,          // [256,2048] fp32 (biases folded)
    const int* __restrict__ tgt,                 // [256,141]
    unsigned short* __restrict__ hs,             // [141,256,512] bf16 (h_1..h_141)
    unsigned* __restrict__ bar)
{
    const int blk = blockIdx.x;
    const int bi  = blk >> 6;        // batch tile 0..3
    const int ht  = blk & 63;        // h tile 0..63
    const int r0  = bi * 64;
    const int h0  = ht * 8;
    const int tid = threadIdx.x;
    const int w    = tid >> 6;
    const int l    = tid & 63;
    const int lr   = l & 15;
    const int quad = l >> 4;
    const int mh = w >> 1;           // m-half 0..1 (which 32 rows)
    const int nf = w & 1;            // n-frag 0..1 (which 16 gate-rows)

    __shared__ unsigned short w_lds[2048 * 8];   // 32 KB fragment-major
    __shared__ float g_lds[64][33];              // gates [row][g*8+hc], padded

    // Stage W slice. Unit u=(nf,k16,quad,lr): 8 bf16 of W row (gr>>3)*512+h0+(gr&7)
    // at cols k16*32+quad*8, where gr = nf*16+lr. Flat unit index == u, so the
    // MFMA-time read addr for lane l is (nf*16+k16)*64 + l  -> conflict-free.
    for (int u = tid; u < 2048; u += 256) {
        const int ulr = u & 15;
        const int uq  = (u >> 4) & 3;
        const int uk  = (u >> 6) & 15;
        const int unf = u >> 10;
        const int gr  = unf * 16 + ulr;
        const int grow = (gr >> 3) * Hdim + h0 + (gr & 7);
        *(bf16x8*)&w_lds[u * 8] =
            *(const bf16x8*)(Whh + (size_t)grow * Hdim + uk * 32 + uq * 8);
    }
    __syncthreads();

    const int prow = tid & 63;           // pointwise: local batch row
    const int phc  = (tid >> 6) * 2;     // pointwise: 2 h-cols
    const int brow = r0 + prow;
    float c0 = 0.f, c1 = 0.f;

    const float* encp = enc_proj + (size_t)brow * G4H + h0;
    const int* tokp   = tgt + (size_t)brow * Sdim;

    const size_t arow0 = (size_t)(r0 + (mh * 2 + 0) * 16 + lr) * Hdim;
    const size_t arow1 = (size_t)(r0 + (mh * 2 + 1) * 16 + lr) * Hdim;
    const unsigned short* wl = w_lds + (size_t)nf * 1024 * 8;

    for (int t = 0; t < Sdim; ++t) {
        f32x4 acc0 = (f32x4){0.f, 0.f, 0.f, 0.f};
        f32x4 acc1 = (f32x4){0.f, 0.f, 0.f, 0.f};
        if (t > 0) {
            const unsigned short* hprev = hs + (size_t)(t - 1) * (Bdim * Hdim);
#pragma unroll
            for (int k16 = 0; k16 < 16; ++k16) {
                const int koff = k16 * 32 + quad * 8;
                bf16x8 a0 = *(const bf16x8*)(hprev + arow0 + koff);
                bf16x8 a1 = *(const bf16x8*)(hprev + arow1 + koff);
                bf16x8 bb = *(const bf16x8*)&wl[(k16 * 64 + l) * 8];
                acc0 = __builtin_amdgcn_mfma_f32_16x16x32_bf16(a0, bb, acc0, 0, 0, 0);
                acc1 = __builtin_amdgcn_mfma_f32_16x16x32_bf16(a1, bb, acc1, 0, 0, 0);
            }
        }
        // C/D: col=lane&15 -> gate-row nf*16+lr; row = quad*4+reg (+ m offsets)
#pragma unroll
        for (int r = 0; r < 4; ++r) {
            g_lds[mh * 32 + quad * 4 + r][nf * 16 + lr]      = acc0[r];
            g_lds[mh * 32 + 16 + quad * 4 + r][nf * 16 + lr] = acc1[r];
        }
        __syncthreads();

        const int tok = tokp[t];
        const unsigned short* embp = emb_proj + (size_t)tok * G4H + h0;
        unsigned hpack = 0;
#pragma unroll
        for (int e = 0; e < 2; ++e) {
            const int hc = phc + e;
            const float iv = g_lds[prow][hc]      + bf2f(embp[hc])              + encp[hc];
            const float fv = g_lds[prow][8 + hc]  + bf2f(embp[Hdim + hc])       + encp[Hdim + hc];
            const float gv = g_lds[prow][16 + hc] + bf2f(embp[2 * Hdim + hc])   + encp[2 * Hdim + hc];
            const float ov = g_lds[prow][24 + hc] + bf2f(embp[3 * Hdim + hc])   + encp[3 * Hdim + hc];
            float c = e ? c1 : c0;
            const float cn = sigmoid_f(fv) * c + sigmoid_f(iv) * tanh_f(gv);
            if (e) c1 = cn; else c0 = cn;
            hpack |= ((unsigned)f2bf(sigmoid_f(ov) * tanh_f(cn))) << (16 * e);
        }
        *(unsigned*)(hs + (size_t)t * (Bdim * Hdim) + (size_t)brow * Hdim + h0 + phc) = hpack;

        if (t != Sdim - 1)
            tile_sync(bar, bi, blk, (unsigned)(t + 1));
    }
}

// ---------------------------------------------------------------------------
// logits = hs[36096,512](bf16) * out_W^T(bf16) + out_b(fp32) -> fp32
// out[b][s][v], row m = s*256 + b.
// ---------------------------------------------------------------------------
__global__ __launch_bounds__(256) void gemm_logits(
    const unsigned short* __restrict__ A,
    const unsigned short* __restrict__ W,
    const float* __restrict__ bias,
    float* __restrict__ out)
{
    const int m0 = blockIdx.x * 128;
    const int n0 = blockIdx.y * 64;
    const int w    = threadIdx.x >> 6;
    const int l    = threadIdx.x & 63;
    const int lr   = l & 15;
    const int quad = l >> 4;

    const unsigned short* pa0 = A + (size_t)(m0 + w * 32 + lr) * Hdim + quad * 8;
    const unsigned short* pa1 = pa0 + (size_t)16 * Hdim;
    const unsigned short* pb[4];
#pragma unroll
    for (int nj = 0; nj < 4; ++nj) {
        int rb = n0 + nj * 16 + lr;
        rb = rb < Vdim ? rb : Vdim - 1;
        pb[nj] = W + (size_t)rb * Hdim + quad * 8;
    }

    f32x4 acc[2][4];
#pragma unroll
    for (int mi = 0; mi < 2; ++mi)
#pragma unroll
        for (int nj = 0; nj < 4; ++nj)
            acc[mi][nj] = (f32x4){0.f, 0.f, 0.f, 0.f};

    for (int k = 0; k < Hdim; k += 32) {
        bf16x8 a0 = *(const bf16x8*)(pa0 + k);
        bf16x8 a1 = *(const bf16x8*)(pa1 + k);
#pragma unroll
        for (int nj = 0; nj < 4; ++nj) {
            bf16x8 bb = *(const bf16x8*)(pb[nj] + k);
            acc[0][nj] = __builtin_amdgcn_mfma_f32_16x16x32_bf16(a0, bb, acc[0][nj], 0, 0, 0);
            acc[1][nj] = __builtin_amdgcn_mfma_f32_16x16x32_bf16(a1, bb, acc[1][nj], 0, 0, 0);
        }
    }

#pragma unroll
    for (int nj = 0; nj < 4; ++nj) {
        const int col = n0 + nj * 16 + lr;
        if (col >= Vdim) continue;
        const float bv = bias[col];
#pragma unroll
        for (int mi = 0; mi < 2; ++mi) {
            const int rowb = m0 + w * 32 + mi * 16 + quad * 4;
#pragma unroll
            for (int r = 0; r < 4; ++r) {
                const int row = rowb + r;            // row = s*256 + b
                const int s = row >> 8;
                const int b = row & 255;
                out[((size_t)b * Sdim + s) * Vdim + col] = acc[mi][nj][r] + bv;
            }
        }
    }
}

extern "C" void kernel_launch(void* const* d_in, const int* in_sizes, int n_in,
                              void* d_out, int out_size, void* d_ws, size_t ws_size,
                              hipStream_t stream) {
    const float* enc   = (const float*)d_in[0];
    const int*   tgt   = (const int*)d_in[1];
    const float* emb   = (const float*)d_in[2];
    const float* W_ih  = (const float*)d_in[3];
    const float* W_hh  = (const float*)d_in[4];
    const float* b_ih  = (const float*)d_in[5];
    const float* b_hh  = (const float*)d_in[6];
    // d_in[7..9]: attn_W / attn_b / v_w — dead code (softmax over 1 source pos)
    const float* out_W = (const float*)d_in[10];
    const float* out_b = (const float*)d_in[11];
    float* out = (float*)d_out;

    char* ws = (char*)d_ws;
    unsigned short* whh_bf   = (unsigned short*)ws;                     // 2,097,152 B
    unsigned short* outw_bf  = (unsigned short*)(ws + 2097152);         // 1,024,000 B
    unsigned short* emb_proj = (unsigned short*)(ws + 3121152);         // 4,096,000 B
    float*          enc_proj = (float*)(ws + 7217152);                  // 2,097,152 B
    unsigned short* hs       = (unsigned short*)(ws + 9314304);         // 36,962,304 B
    unsigned*       bar      = (unsigned*)(ws + 46276608);              // 4,096 B
    // total ws use = 46,280,704 B

    hipMemsetAsync(bar, 0, 4096, stream);   // barrier counters (re-poisoned each call)

    f32_to_bf16_4<<<dim3((262144 + 255) / 256), 256, 0, stream>>>(
        (const float4*)W_hh, (u16x4*)whh_bf, 262144);
    f32_to_bf16_4<<<dim3((128000 + 255) / 256), 256, 0, stream>>>(
        (const float4*)out_W, (u16x4*)outw_bf, 128000);

    // emb_proj = embedding @ W_ih[:, :E].T               (bf16, [1000,2048])
    gemm_bt_f32in<true><<<dim3(8, 32), 256, 0, stream>>>(
        emb, Edim, Vdim, W_ih, 2 * Edim, emb_proj, G4H, nullptr, nullptr, Edim);
    // enc_proj = encoder_output @ W_ih[:, E:].T + b_ih + b_hh   (fp32, [256,2048])
    gemm_bt_f32in<false><<<dim3(2, 32), 256, 0, stream>>>(
        enc, Edim, Bdim, W_ih + Edim, 2 * Edim, enc_proj, G4H, b_ih, b_hh, Edim);
    // weights-stationary scan: 256 blocks, per-batch-tile barrier
    lstm_scan<<<dim3(256), 256, 0, stream>>>(whh_bf, emb_proj, enc_proj, tgt, hs, bar);
    // logits = hs @ out_W.T + out_b   (fp32 out)
    gemm_logits<<<dim3(282, 16), 256, 0, stream>>>(hs, outw_bf, out_b, out);
}